// Round 17
// baseline (174.308 us; speedup 1.0000x reference)
//
#include <hip/hip_runtime.h>
#include <hip/hip_bf16.h>

// ---------------- problem constants ----------------
constexpr int Bn = 8, Cn = 128, Hn = 64, Wn = 64, HWn = Hn * Wn;
constexpr int DGn = 8, Kn = 9, CMn = 216;          // CM = DG*3*K
constexpr int Hs = 32, Ws = 32, HWs = Hs * Ws;

typedef __attribute__((ext_vector_type(8))) short bf16x8;
typedef __attribute__((ext_vector_type(4))) float f32x4;

// ---------------- workspace layout (float offsets) ----------------
constexpr long OFF_FLAG = 0;                              // int flag (256 floats)
constexpr long OFF_FLB  = 256;                            // feat_l bf16 NHWC [8][4096][128]
constexpr long OFF_FUPB = OFF_FLB  + (long)Bn*HWn*Cn/2;   // fup bf16 NHWC
constexpr long OFF_OFT  = OFF_FUPB + (long)Bn*HWn*Cn/2;   // off_feat bf16 NHWC
constexpr long OFF_WCT  = OFF_OFT  + (long)Bn*HWn*Cn/2;   // w_cm bf16 slices [18][224][128B-swz]
constexpr long OFF_WDT  = OFF_WCT  + (long)18*224*64/2 + 64;  // w_dcn bf16 [k][ks][o][lh][8]
constexpr long OFF_P    = OFF_WDT  + (long)Kn*Cn*Cn/2 + 64;   // P f32 [128][128]
constexpr long OFF_W1TB = OFF_P    + 16384;               // w1tb bf16 [b][o][c]
constexpr long OFF_WCAT = OFF_W1TB + (long)Bn*Cn*Cn/2;    // wcat bf16 [b][o][256]
constexpr long OFF_BCM  = OFF_WCAT + (long)Bn*Cn*256/2;   // b_cm f32 (256)
constexpr long OFF_BDC  = OFF_BCM + 256;                  // b_dcn f32 (256)
constexpr long OFF_GAP  = OFF_BDC + 256;                  // gap f32 [b][c] (1024)
constexpr long OFF_AT   = OFF_GAP + 1024;                 // 1+sigmoid(atten) (1024)
constexpr long OFF_FARM = OFF_AT  + 1024;                 // feat_arm bf16 NCHW [8][128][4096]
constexpr long OFF_OM   = OFF_FARM + (long)Bn*Cn*HWn;     // om bf16 [b][h][216][64]

static __device__ __forceinline__ float ldin(const void* p, long i, bool isbf) {
  if (isbf) return __bfloat162float(((const __hip_bfloat16*)p)[i]);
  return ((const float*)p)[i];
}
static __device__ __forceinline__ unsigned short f2b(float f) {
  unsigned u = __builtin_bit_cast(unsigned, f);
  u += 0x7FFFu + ((u >> 16) & 1u);
  return (unsigned short)(u >> 16);
}
static __device__ __forceinline__ unsigned pack2(float v0, float v1) {
  return ((unsigned)f2b(v1) << 16) | (unsigned)f2b(v0);
}
static __device__ __forceinline__ float b2f(unsigned short s) {
  return __builtin_bit_cast(float, ((unsigned)s) << 16);
}

#define GLOAD_LDS16(g, l) __builtin_amdgcn_global_load_lds( \
    (const __attribute__((address_space(1))) void*)(g),     \
    (__attribute__((address_space(3))) void*)(l), 16, 0, 0)

// ---------------- dtype detector + gap zeroing ----------------
__global__ __launch_bounds__(256) void k_detect(const unsigned int* __restrict__ p,
                                                int* __restrict__ flag,
                                                float* __restrict__ gap) {
  __shared__ int cnt[256];
  int t = threadIdx.x;
  int c = 0;
  for (int i = 0; i < 4; ++i) {
    unsigned v = p[t * 4 + i];
    unsigned e = (v >> 7) & 0xFFu;
    c += (e >= 118u && e <= 130u) ? 1 : 0;
  }
  cnt[t] = c;
#pragma unroll
  for (int i = 0; i < 4; ++i) gap[t + i * 256] = 0.f;
  __syncthreads();
  for (int s = 128; s > 0; s >>= 1) {
    if (t < s) cnt[t] += cnt[t + s];
    __syncthreads();
  }
  if (t == 0) *flag = (cnt[0] > 512) ? 1 : 0;
}

// ---------------- merged prep: biases / w_cm / w_dcn / P ----------------
__global__ __launch_bounds__(256) void k_prep(const void* __restrict__ b_cm,
                                              const void* __restrict__ b_dcn,
                                              const void* __restrict__ w_cm,
                                              const void* __restrict__ w_dcn,
                                              const void* __restrict__ woff,
                                              const void* __restrict__ wfsm,
                                              float* __restrict__ bcm_d,
                                              float* __restrict__ bdc_d,
                                              unsigned short* __restrict__ wcb,
                                              unsigned short* __restrict__ wdb,
                                              float* __restrict__ P,
                                              const int* __restrict__ flag) {
  const int bid = blockIdx.x, t = threadIdx.x;
  const bool isbf = (*flag != 0);
  if (bid == 0) {
    if (t < CMn) bcm_d[t] = ldin(b_cm, t, isbf);
    if (t < Cn)  bdc_d[t] = ldin(b_dcn, t, isbf);
    return;
  }
  if (bid < 1 + 1008) {                       // w_cm -> [18][224][128B swz]
    int i = (bid - 1) * 256 + t;
    if (i >= 18 * 224 * 64) return;
    int s = i / (224 * 64);
    int rem = i % (224 * 64);
    int oc = rem >> 6, c_off = rem & 63;
    int tap = s >> 1, ck = s & 1;
    int c = ck * 64 + c_off;
    float v = 0.f;
    if (oc < CMn) v = ldin(w_cm, ((long)oc * Cn + c) * Kn + tap, isbf);
    int chunk = c_off >> 3, e = c_off & 7;
    int pc = chunk ^ (oc & 7);
    wcb[(long)s * 14336 + oc * 64 + pc * 8 + e] = f2b(v);
    return;
  }
  if (bid < 1 + 1008 + 576) {                 // w_dcn -> [k][ks][o][lh][8]
    int i = (bid - 1 - 1008) * 256 + t;
    if (i >= Kn * Cn * Cn) return;
    int e = i & 7, lh = (i >> 3) & 3, o = (i >> 5) & 127;
    int ks = (i >> 12) & 3, k = i >> 14;
    int c = ks * 32 + lh * 8 + e;
    wdb[i] = f2b(ldin(w_dcn, ((long)o * Cn + c) * Kn + k, isbf));
    return;
  }
  {                                           // P = w_off[:, :128] @ w_fsm
    int idx = (bid - 1 - 1008 - 576) * 256 + t;
    if (idx >= Cn * Cn) return;
    int o = idx >> 7, k = idx & 127;
    float s = 0.f;
    for (int c = 0; c < Cn; ++c)
      s += ldin(woff, (long)o * 256 + c, isbf) * ldin(wfsm, (long)c * Cn + k, isbf);
    P[idx] = s;
  }
}

// ---------------- fused feat_l->flb (+gap) and feat_s->fupb ----------------
__global__ __launch_bounds__(256) void k_cvtlup(const void* __restrict__ feat_l,
                                                const void* __restrict__ fs,
                                                unsigned short* __restrict__ flb,
                                                unsigned short* __restrict__ fupb,
                                                float* __restrict__ gap,
                                                const int* __restrict__ flag) {
  __shared__ float sh[8448];
  const int b = blockIdx.y, t = threadIdx.x;
  const bool isbf = (*flag != 0);
  if (blockIdx.z == 0) {
    const int p0 = blockIdx.x * 64;
    for (int i = t; i < 8192; i += 256) {
      int c = i >> 6, p = i & 63;
      sh[c * 65 + p] = ldin(feat_l, (long)(b * Cn + c) * HWn + p0 + p, isbf);
    }
    __syncthreads();
    if (t < 128) {
      float s = 0.f;
#pragma unroll
      for (int p = 0; p < 64; ++p) s += sh[t * 65 + p];
      atomicAdd(&gap[b * Cn + t], s * (1.0f / HWn));
    }
    for (int i = t; i < 1024; i += 256) {
      int p = i >> 4, ch = (i & 15) * 8;
      uint4 pk;
      pk.x = pack2(sh[(ch + 0) * 65 + p], sh[(ch + 1) * 65 + p]);
      pk.y = pack2(sh[(ch + 2) * 65 + p], sh[(ch + 3) * 65 + p]);
      pk.z = pack2(sh[(ch + 4) * 65 + p], sh[(ch + 5) * 65 + p]);
      pk.w = pack2(sh[(ch + 6) * 65 + p], sh[(ch + 7) * 65 + p]);
      *(uint4*)(flb + (((long)(b * HWn + p0 + p)) << 7) + ch) = pk;
    }
  } else {
    const int h = blockIdx.x;
    int iy0; float fy;
    if (h & 1) { iy0 = (h - 1) >> 1; fy = 0.25f; } else { iy0 = (h >> 1) - 1; fy = 0.75f; }
    int iy1 = min(iy0 + 1, Hs - 1); iy0 = max(iy0, 0);
    for (int i = t; i < 8192; i += 256) {
      int sel = i >> 12, c = (i >> 5) & 127, x = i & 31;
      int iy = sel ? iy1 : iy0;
      sh[sel * 4224 + c * 33 + x] = ldin(fs, (long)(b * Cn + c) * HWs + iy * Ws + x, isbf);
    }
    __syncthreads();
    for (int i = t; i < 1024; i += 256) {
      int w = i >> 4, ch0 = (i & 15) * 8;
      int ix0; float fx;
      if (w & 1) { ix0 = (w - 1) >> 1; fx = 0.25f; } else { ix0 = (w >> 1) - 1; fx = 0.75f; }
      int ix1 = min(ix0 + 1, Ws - 1); ix0 = max(ix0, 0);
      float v[8];
#pragma unroll
      for (int j = 0; j < 8; ++j) {
        int c = ch0 + j;
        v[j] = (1.f - fy) * ((1.f - fx) * sh[c * 33 + ix0] + fx * sh[c * 33 + ix1]) +
               fy         * ((1.f - fx) * sh[4224 + c * 33 + ix0] + fx * sh[4224 + c * 33 + ix1]);
      }
      uint4 pk;
      pk.x = pack2(v[0], v[1]); pk.y = pack2(v[2], v[3]);
      pk.z = pack2(v[4], v[5]); pk.w = pack2(v[6], v[7]);
      *(uint4*)(fupb + (((long)(b * HWn + h * Wn + w)) << 7) + ch0) = pk;
    }
  }
}

// ---------------- atten ----------------
__global__ __launch_bounds__(256) void k_atten(const float* __restrict__ gap,
                                               const void* __restrict__ wat,
                                               float* __restrict__ at1p,
                                               const int* __restrict__ flag) {
  int tid = blockIdx.x * 256 + threadIdx.x;
  if (tid >= Bn * Cn) return;
  int b = tid >> 7, o = tid & 127;
  bool isbf = (*flag != 0);
  const float* g = gap + b * Cn;
  float s = 0.f;
  for (int c = 0; c < Cn; ++c) s += g[c] * ldin(wat, (long)o * Cn + c, isbf);
  at1p[tid] = 1.0f + 1.0f / (1.0f + expf(-s));
}

// ---------------- per-batch weight prep ----------------
__global__ __launch_bounds__(256) void k_wprep(const void* __restrict__ wfsm,
                                               const void* __restrict__ woff,
                                               const float* __restrict__ P,
                                               const float* __restrict__ at1p,
                                               unsigned short* __restrict__ w1tb,
                                               unsigned short* __restrict__ wcat,
                                               const int* __restrict__ flag) {
  int idx = blockIdx.x * 256 + threadIdx.x;
  if (idx >= Bn * 49152) return;
  bool isbf = (*flag != 0);
  int b = idx / 49152, r = idx % 49152;
  if (r < 16384) {
    int o = r >> 7, k = r & 127;
    w1tb[((long)(b * Cn + o) << 7) + k] =
        f2b(ldin(wfsm, (long)o * Cn + k, isbf) * at1p[b * Cn + k]);
  } else {
    r -= 16384;
    int o = r >> 8, k = r & 255;
    float v = (k < 128) ? P[o * Cn + k] * at1p[b * Cn + k]
                        : 2.0f * ldin(woff, (long)o * 256 + k, isbf);
    wcat[((long)(b * Cn + o) << 8) + k] = f2b(v);
  }
}

// ---------------- fused feat_arm + off_feat via MFMA (M-tile 32) ----------------
__global__ __launch_bounds__(256) void k_fao(const unsigned short* __restrict__ flb,
                                             const unsigned short* __restrict__ fupb,
                                             const unsigned short* __restrict__ w1tb,
                                             const unsigned short* __restrict__ wcat,
                                             unsigned short* __restrict__ farm,
                                             unsigned short* __restrict__ oftb) {
  const int b = blockIdx.y, m0 = blockIdx.x * 32;
  const int t = threadIdx.x, lane = t & 63, wv = t >> 6;
  const int lm = lane & 15, lh = lane >> 4;
  f32x4 accF[2][2], accO[2][2];
#pragma unroll
  for (int mt = 0; mt < 2; ++mt)
#pragma unroll
    for (int nt = 0; nt < 2; ++nt) {
      accF[mt][nt] = (f32x4){0.f, 0.f, 0.f, 0.f};
      accO[mt][nt] = (f32x4){0.f, 0.f, 0.f, 0.f};
    }
  const unsigned short* A0 = flb + ((long)b << 19);
  const unsigned short* A1 = fupb + ((long)b << 19);
  const unsigned short* BwF = w1tb + ((long)b << 14);
  const unsigned short* BwO = wcat + ((long)b << 15);
#pragma unroll
  for (int ks = 0; ks < 4; ++ks) {
    int c0 = ks * 32 + lh * 8;
    bf16x8 bfvF[2], bfvO[2];
#pragma unroll
    for (int nt = 0; nt < 2; ++nt) {
      int o = wv * 32 + nt * 16 + lm;
      bfvF[nt] = *(const bf16x8*)(BwF + ((long)o << 7) + c0);
      bfvO[nt] = *(const bf16x8*)(BwO + ((long)o << 8) + c0);
    }
#pragma unroll
    for (int mt = 0; mt < 2; ++mt) {
      bf16x8 af = *(const bf16x8*)(A0 + (((long)(m0 + mt * 16 + lm)) << 7) + c0);
#pragma unroll
      for (int nt = 0; nt < 2; ++nt) {
        accF[mt][nt] = __builtin_amdgcn_mfma_f32_16x16x32_bf16(af, bfvF[nt], accF[mt][nt], 0, 0, 0);
        accO[mt][nt] = __builtin_amdgcn_mfma_f32_16x16x32_bf16(af, bfvO[nt], accO[mt][nt], 0, 0, 0);
      }
    }
  }
#pragma unroll
  for (int ks = 4; ks < 8; ++ks) {
    int c0 = ks * 32 + lh * 8;
    int ca = c0 - 128;
    bf16x8 bfvO[2];
#pragma unroll
    for (int nt = 0; nt < 2; ++nt)
      bfvO[nt] = *(const bf16x8*)(BwO + (((long)(wv * 32 + nt * 16 + lm)) << 8) + c0);
#pragma unroll
    for (int mt = 0; mt < 2; ++mt) {
      bf16x8 af = *(const bf16x8*)(A1 + (((long)(m0 + mt * 16 + lm)) << 7) + ca);
#pragma unroll
      for (int nt = 0; nt < 2; ++nt)
        accO[mt][nt] = __builtin_amdgcn_mfma_f32_16x16x32_bf16(af, bfvO[nt], accO[mt][nt], 0, 0, 0);
    }
  }
#pragma unroll
  for (int nt = 0; nt < 2; ++nt) {
    int o = wv * 32 + nt * 16 + lm;
#pragma unroll
    for (int mt = 0; mt < 2; ++mt) {
      uint2 pw;
      pw.x = pack2(accF[mt][nt][0], accF[mt][nt][1]);
      pw.y = pack2(accF[mt][nt][2], accF[mt][nt][3]);
      *(uint2*)(farm + (((long)(b * Cn + o)) << 12) + m0 + mt * 16 + lh * 4) = pw;
#pragma unroll
      for (int r = 0; r < 4; ++r)
        oftb[(((long)(b * HWn + m0 + mt * 16 + lh * 4 + r)) << 7) + o] = f2b(accO[mt][nt][r]);
    }
  }
}

// ---------------- 3x3 conv via bf16 MFMA -> om (bf16), XCD-localized ----------------
__global__ __launch_bounds__(256) void k_convcm(const unsigned short* __restrict__ xb,
                                                const unsigned short* __restrict__ wsl,
                                                const float* __restrict__ bcm,
                                                unsigned short* __restrict__ om) {
  __shared__ unsigned short wlds[2][14336];
  const int bid = blockIdx.x;
  const int b = bid & 7, h = bid >> 3;
  const int t = threadIdx.x, lane = t & 63, wv = t >> 6;
  const int mi = wv & 1, ni = wv >> 1;
  const int lm = lane & 15, lh = lane >> 4;

  f32x4 acc[2][7];
#pragma unroll
  for (int mt = 0; mt < 2; ++mt)
#pragma unroll
    for (int nt = 0; nt < 7; ++nt) acc[mt][nt] = (f32x4){0.f, 0.f, 0.f, 0.f};

  auto stage = [&](int s, int bufi) {
    const char* src = (const char*)(wsl + (long)s * 14336);
    char* dstb = (char*)&wlds[bufi][0];
#pragma unroll
    for (int i2 = 0; i2 < 7; ++i2) {
      int off = (wv * 7 + i2) * 1024;
      GLOAD_LDS16(src + off + lane * 16, dstb + off);
    }
  };

  stage(0, 0);
  __syncthreads();

  for (int s = 0; s < 18; ++s) {
    const int cur = s & 1;
    if (s < 17) stage(s + 1, cur ^ 1);
    const int tap = s >> 1, ck = s & 1;
    const int ky = tap / 3, kx = tap % 3;
    const int gy = h + ky - 1;
    const bool gyok = ((unsigned)gy < (unsigned)Hn);
    const int gyc = min(max(gy, 0), Hn - 1);

    bf16x8 af[2][2];
#pragma unroll
    for (int mt = 0; mt < 2; ++mt) {
      int wpos = mi * 32 + mt * 16 + lm;
      int gx = wpos + kx - 1;
      bool ok = gyok && ((unsigned)gx < (unsigned)Wn);
      int gxc = min(max(gx, 0), Wn - 1);
      const unsigned short* ap = xb + (((long)(b * HWn + gyc * Wn + gxc)) << 7)
                                    + ck * 64 + lh * 8;
#pragma unroll
      for (int ksub = 0; ksub < 2; ++ksub) {
        bf16x8 v = *(const bf16x8*)(ap + ksub * 32);
        af[mt][ksub] = ok ? v : (bf16x8)(short)0;
      }
    }

    const char* wbase = (const char*)&wlds[cur][0];
#pragma unroll
    for (int ksub = 0; ksub < 2; ++ksub) {
      int jj = ksub * 4 + lh;
#pragma unroll
      for (int nt = 0; nt < 7; ++nt) {
        int oc = ni * 112 + nt * 16 + lm;
        bf16x8 bfv = *(const bf16x8*)(wbase + oc * 128 + ((jj ^ (oc & 7)) << 4));
#pragma unroll
        for (int mt = 0; mt < 2; ++mt)
          acc[mt][nt] = __builtin_amdgcn_mfma_f32_16x16x32_bf16(
              af[mt][ksub], bfv, acc[mt][nt], 0, 0, 0);
      }
    }
    __syncthreads();
  }

#pragma unroll
  for (int nt = 0; nt < 7; ++nt) {
    int ch = ni * 112 + nt * 16 + lm;
    if (ch >= CMn) continue;
    float bias = bcm[ch];
#pragma unroll
    for (int mt = 0; mt < 2; ++mt) {
#pragma unroll
      for (int r = 0; r < 4; ++r) {
        int w = mi * 32 + mt * 16 + lh * 4 + r;
        float v = acc[mt][nt][r] + bias;
        if (ch >= 144) v = 1.0f / (1.0f + expf(-v));
        om[((long)((b * Hn + h) * CMn + ch) << 6) + w] = f2b(v);
      }
    }
  }
}

// ---------------- fused DCN v2: producer/consumer, issue-all-then-consume ----------------
// grid = 1024 1D blocks; b = bid&7 pins each batch's slices to one XCD.
// stage(): phase 1 issues ALL 8 corner loads (both groups) before any bilinear
// VALU -> group-1 load latency hides under group-0 math.
__global__ __launch_bounds__(512, 6) void k_dcn(const unsigned short* __restrict__ omb,
                                                const unsigned short* __restrict__ fupb,
                                                const unsigned short* __restrict__ wdb,
                                                const float* __restrict__ bdc,
                                                const unsigned short* __restrict__ farm,
                                                void* __restrict__ out,
                                                const int* __restrict__ flagp) {
  __shared__ char smem[13824 + 16384];
  unsigned short* om16 = (unsigned short*)smem;       // [216][32] bf16
  const int bid = blockIdx.x;
  const int b = bid & 7, hw = bid >> 3;
  const int h = hw >> 1, w0 = (hw & 1) * 32;
  const int t = threadIdx.x;
  const int lane = t & 63, wid = t >> 6;
  const int lm = lane & 15, lh = lane >> 4;

  // ---- om preload: 216 rows x 32 bf16 ----
  const unsigned short* omr = omb + ((long)(b * Hn + h) * CMn << 6) + w0;
  for (int i = t; i < 864; i += 512) {
    int ch = i >> 2, q = i & 3;
    *(uint4*)(om16 + ch * 32 + q * 8) = *(const uint4*)(omr + (ch << 6) + q * 8);
  }

  // producer identity: lane pairs share corner lines
  const int pid = (wid << 6) | lane;
  const int half = pid & 1, gw = (pid >> 1) & 31, gg = pid >> 6;
  const int wcol = w0 + gw;
  const unsigned short* fbb = fupb + ((long)b << 19) + half * 8;

  // consumer identity
  const int cw = wid - 4;
  f32x4 acc[2][2];
#pragma unroll
  for (int mt = 0; mt < 2; ++mt)
#pragma unroll
    for (int nt = 0; nt < 2; ++nt) acc[mt][nt] = (f32x4){0.f, 0.f, 0.f, 0.f};

  union U4 { uint4 q; unsigned short s[8]; };

  auto stage = [&](int k) {
    U4 r[2][4];
    float wqs[2][4];
    // phase 1: addresses + issue ALL 8 loads
#pragma unroll
    for (int ti = 0; ti < 2; ++ti) {
      const int g = gg + ti * 4;
      const unsigned short* fb = fbb + g * 16;
      int ch = g * Kn + k;
      float oy = b2f(om16[ch * 32 + gw]);
      float ox = b2f(om16[(72 + ch) * 32 + gw]);
      float mk = b2f(om16[(144 + ch) * 32 + gw]);
      float py = (float)(h + k / 3 - 1) + oy;
      float px = (float)(wcol + k % 3 - 1) + ox;
      float fy = floorf(py), fx = floorf(px);
      float ly = py - fy, lx = px - fx;
      int y0 = (int)fy, x0 = (int)fx, y1 = y0 + 1, x1 = x0 + 1;
      float vy0 = (y0 >= 0 && y0 < Hn) ? 1.f : 0.f;
      float vy1 = (y1 >= 0 && y1 < Hn) ? 1.f : 0.f;
      float vx0 = (x0 >= 0 && x0 < Wn) ? 1.f : 0.f;
      float vx1 = (x1 >= 0 && x1 < Wn) ? 1.f : 0.f;
      int cy0 = min(max(y0, 0), Hn - 1), cy1 = min(max(y1, 0), Hn - 1);
      int cx0 = min(max(x0, 0), Wn - 1), cx1 = min(max(x1, 0), Wn - 1);
      wqs[ti][0] = (1.f - ly) * (1.f - lx) * vy0 * vx0 * mk;
      wqs[ti][1] = (1.f - ly) * lx * vy0 * vx1 * mk;
      wqs[ti][2] = ly * (1.f - lx) * vy1 * vx0 * mk;
      wqs[ti][3] = ly * lx * vy1 * vx1 * mk;
      r[ti][0].q = *(const uint4*)(fb + ((long)(cy0 * Wn + cx0) << 7));
      r[ti][1].q = *(const uint4*)(fb + ((long)(cy0 * Wn + cx1) << 7));
      r[ti][2].q = *(const uint4*)(fb + ((long)(cy1 * Wn + cx0) << 7));
      r[ti][3].q = *(const uint4*)(fb + ((long)(cy1 * Wn + cx1) << 7));
    }
    // phase 2: bilinear + pack + LDS write
#pragma unroll
    for (int ti = 0; ti < 2; ++ti) {
      const int g = gg + ti * 4;
      float v[8];
#pragma unroll
      for (int j = 0; j < 8; ++j)
        v[j] = wqs[ti][0] * b2f(r[ti][0].s[j]) + wqs[ti][1] * b2f(r[ti][1].s[j]) +
               wqs[ti][2] * b2f(r[ti][2].s[j]) + wqs[ti][3] * b2f(r[ti][3].s[j]);
      uint4 pk;
      pk.x = pack2(v[0], v[1]); pk.y = pack2(v[2], v[3]);
      pk.z = pack2(v[4], v[5]); pk.w = pack2(v[6], v[7]);
      int chunk = g * 2 + half;
      *(uint4*)(smem + 13824 + (k & 1) * 8192 + gw * 256 + ((chunk ^ (gw & 15)) << 4)) = pk;
    }
  };

  __syncthreads();            // om16 ready
  if (wid < 4) stage(0);
  __syncthreads();            // buf0 ready

#pragma unroll
  for (int k = 0; k < Kn; ++k) {
    if (wid < 4) {
      if (k < Kn - 1) stage(k + 1);
    } else {
      const char* base = smem + 13824 + (k & 1) * 8192;
      const unsigned short* wk = wdb + (long)k * 16384;
      __builtin_amdgcn_s_setprio(1);
#pragma unroll
      for (int ks = 0; ks < 4; ++ks) {
        int rchunk = (ks * 4 + lh) ^ lm;
        bf16x8 af0 = *(const bf16x8*)(base + lm * 256 + (rchunk << 4));
        bf16x8 af1 = *(const bf16x8*)(base + (16 + lm) * 256 + (rchunk << 4));
#pragma unroll
        for (int nt = 0; nt < 2; ++nt) {
          bf16x8 bfv = *(const bf16x8*)(wk + ks * 4096 +
                                        ((cw * 32 + nt * 16 + lm) << 5) + lh * 8);
          acc[0][nt] = __builtin_amdgcn_mfma_f32_16x16x32_bf16(af0, bfv, acc[0][nt], 0, 0, 0);
          acc[1][nt] = __builtin_amdgcn_mfma_f32_16x16x32_bf16(af1, bfv, acc[1][nt], 0, 0, 0);
        }
      }
      __builtin_amdgcn_s_setprio(0);
    }
    __syncthreads();
  }

  // ---- epilogue: acc -> padded LDS -> w-major coalesced farm+out ----
  float* eps = (float*)smem;
  if (wid >= 4) {
#pragma unroll
    for (int nt = 0; nt < 2; ++nt) {
      int o = cw * 32 + nt * 16 + lm;
#pragma unroll
      for (int mt = 0; mt < 2; ++mt)
#pragma unroll
        for (int r = 0; r < 4; ++r)
          eps[o * 33 + mt * 16 + lh * 4 + r] = acc[mt][nt][r];
    }
  }
  __syncthreads();
  {
    bool isbf = (*flagp != 0);
    int o = t >> 2, q = t & 3;            // 128 o x 4 q(8w each)
    float bias = bdc[o];
    long obase = (long)(b * Cn + o) * HWn + h * Wn + w0 + q * 8;
    U4 fv;
    fv.q = *(const uint4*)(farm + obase);
    float vout[8];
#pragma unroll
    for (int j = 0; j < 8; ++j) {
      float v = eps[o * 33 + q * 8 + j] + bias;
      vout[j] = fmaxf(v, 0.f) + b2f(fv.s[j]);
    }
    if (isbf) {
      uint4 pk;
      pk.x = pack2(vout[0], vout[1]); pk.y = pack2(vout[2], vout[3]);
      pk.z = pack2(vout[4], vout[5]); pk.w = pack2(vout[6], vout[7]);
      *(uint4*)((__hip_bfloat16*)out + obase) = pk;
    } else {
      float* op = (float*)out + obase;
      *(float4*)op = (float4){vout[0], vout[1], vout[2], vout[3]};
      *(float4*)(op + 4) = (float4){vout[4], vout[5], vout[6], vout[7]};
    }
  }
}

// ---------------- launcher ----------------
extern "C" void kernel_launch(void* const* d_in, const int* in_sizes, int n_in,
                              void* d_out, int out_size, void* d_ws, size_t ws_size,
                              hipStream_t stream) {
  (void)in_sizes; (void)n_in; (void)out_size; (void)ws_size;
  const void* feat_l  = d_in[0];
  const void* feat_s  = d_in[1];
  const void* w_atten = d_in[2];
  const void* w_fsm   = d_in[3];
  const void* w_off   = d_in[4];
  const void* w_cm    = d_in[5];
  const void* b_cm    = d_in[6];
  const void* w_dcn   = d_in[7];
  const void* b_dcn   = d_in[8];
  float* ws = (float*)d_ws;
  int* flagw = (int*)d_ws;
  const int* flag = (const int*)d_ws;
  unsigned short* flb  = (unsigned short*)(ws + OFF_FLB);
  unsigned short* fupb = (unsigned short*)(ws + OFF_FUPB);
  unsigned short* oftb = (unsigned short*)(ws + OFF_OFT);
  unsigned short* wcb  = (unsigned short*)(ws + OFF_WCT);
  unsigned short* wdb  = (unsigned short*)(ws + OFF_WDT);
  unsigned short* w1tb = (unsigned short*)(ws + OFF_W1TB);
  unsigned short* wcat = (unsigned short*)(ws + OFF_WCAT);
  unsigned short* farm = (unsigned short*)(ws + OFF_FARM);
  unsigned short* omb  = (unsigned short*)(ws + OFF_OM);

  k_detect<<<1, 256, 0, stream>>>((const unsigned int*)feat_l, flagw, ws + OFF_GAP);
  k_prep<<<1 + 1008 + 576 + 64, 256, 0, stream>>>(b_cm, b_dcn, w_cm, w_dcn,
                                                  w_off, w_fsm,
                                                  ws + OFF_BCM, ws + OFF_BDC,
                                                  wcb, wdb, ws + OFF_P, flag);
  k_cvtlup<<<dim3(64, 8, 2), 256, 0, stream>>>(feat_l, feat_s, flb, fupb,
                                               ws + OFF_GAP, flag);
  k_atten<<<4, 256, 0, stream>>>(ws + OFF_GAP, w_atten, ws + OFF_AT, flag);
  k_wprep<<<(Bn * 49152 + 255) / 256, 256, 0, stream>>>(w_fsm, w_off, ws + OFF_P,
                                                        ws + OFF_AT, w1tb, wcat, flag);
  k_fao<<<dim3(128, 8), 256, 0, stream>>>(flb, fupb, w1tb, wcat, farm, oftb);
  k_convcm<<<512, 256, 0, stream>>>(oftb, wcb, ws + OFF_BCM, omb);
  k_dcn<<<1024, 512, 0, stream>>>(omb, fupb, wdb, ws + OFF_BDC, farm, d_out, flag);
}

// Round 18
// 169.479 us; speedup vs baseline: 1.0285x; 1.0285x over previous
//
#include <hip/hip_runtime.h>
#include <hip/hip_bf16.h>

// ---------------- problem constants ----------------
constexpr int Bn = 8, Cn = 128, Hn = 64, Wn = 64, HWn = Hn * Wn;
constexpr int DGn = 8, Kn = 9, CMn = 216;          // CM = DG*3*K
constexpr int Hs = 32, Ws = 32, HWs = Hs * Ws;

typedef __attribute__((ext_vector_type(8))) short bf16x8;
typedef __attribute__((ext_vector_type(4))) float f32x4;

// ---------------- workspace layout (float offsets) ----------------
constexpr long OFF_FLAG = 0;                              // int flag (256 floats)
constexpr long OFF_FLB  = 256;                            // feat_l bf16 NHWC [8][4096][128]
constexpr long OFF_FUPB = OFF_FLB  + (long)Bn*HWn*Cn/2;   // fup bf16 NHWC
constexpr long OFF_OFT  = OFF_FUPB + (long)Bn*HWn*Cn/2;   // off_feat bf16 NHWC
constexpr long OFF_WCT  = OFF_OFT  + (long)Bn*HWn*Cn/2;   // w_cm bf16 slices [18][224][128B-swz]
constexpr long OFF_WDT  = OFF_WCT  + (long)18*224*64/2 + 64;  // w_dcn bf16 [k][ks][o][lh][8]
constexpr long OFF_P    = OFF_WDT  + (long)Kn*Cn*Cn/2 + 64;   // P f32 [128][128]
constexpr long OFF_W1TB = OFF_P    + 16384;               // w1tb bf16 [b][o][c]
constexpr long OFF_WCAT = OFF_W1TB + (long)Bn*Cn*Cn/2;    // wcat bf16 [b][o][256]
constexpr long OFF_BCM  = OFF_WCAT + (long)Bn*Cn*256/2;   // b_cm f32 (256)
constexpr long OFF_BDC  = OFF_BCM + 256;                  // b_dcn f32 (256)
constexpr long OFF_GAP  = OFF_BDC + 256;                  // gap f32 [b][c] (1024)
constexpr long OFF_AT   = OFF_GAP + 1024;                 // 1+sigmoid(atten) (1024)
constexpr long OFF_FARM = OFF_AT  + 1024;                 // feat_arm bf16 NCHW [8][128][4096]
constexpr long OFF_OM   = OFF_FARM + (long)Bn*Cn*HWn;     // om bf16 [b][h][216][64]

static __device__ __forceinline__ float ldin(const void* p, long i, bool isbf) {
  if (isbf) return __bfloat162float(((const __hip_bfloat16*)p)[i]);
  return ((const float*)p)[i];
}
static __device__ __forceinline__ unsigned short f2b(float f) {
  unsigned u = __builtin_bit_cast(unsigned, f);
  u += 0x7FFFu + ((u >> 16) & 1u);
  return (unsigned short)(u >> 16);
}
static __device__ __forceinline__ unsigned pack2(float v0, float v1) {
  return ((unsigned)f2b(v1) << 16) | (unsigned)f2b(v0);
}
static __device__ __forceinline__ float b2f(unsigned short s) {
  return __builtin_bit_cast(float, ((unsigned)s) << 16);
}

#define GLOAD_LDS16(g, l) __builtin_amdgcn_global_load_lds( \
    (const __attribute__((address_space(1))) void*)(g),     \
    (__attribute__((address_space(3))) void*)(l), 16, 0, 0)

// ---------------- dtype detector + gap zeroing ----------------
__global__ __launch_bounds__(256) void k_detect(const unsigned int* __restrict__ p,
                                                int* __restrict__ flag,
                                                float* __restrict__ gap) {
  __shared__ int cnt[256];
  int t = threadIdx.x;
  int c = 0;
  for (int i = 0; i < 4; ++i) {
    unsigned v = p[t * 4 + i];
    unsigned e = (v >> 7) & 0xFFu;
    c += (e >= 118u && e <= 130u) ? 1 : 0;
  }
  cnt[t] = c;
#pragma unroll
  for (int i = 0; i < 4; ++i) gap[t + i * 256] = 0.f;
  __syncthreads();
  for (int s = 128; s > 0; s >>= 1) {
    if (t < s) cnt[t] += cnt[t + s];
    __syncthreads();
  }
  if (t == 0) *flag = (cnt[0] > 512) ? 1 : 0;
}

// ---------------- merged prep: biases / w_cm / w_dcn / P ----------------
__global__ __launch_bounds__(256) void k_prep(const void* __restrict__ b_cm,
                                              const void* __restrict__ b_dcn,
                                              const void* __restrict__ w_cm,
                                              const void* __restrict__ w_dcn,
                                              const void* __restrict__ woff,
                                              const void* __restrict__ wfsm,
                                              float* __restrict__ bcm_d,
                                              float* __restrict__ bdc_d,
                                              unsigned short* __restrict__ wcb,
                                              unsigned short* __restrict__ wdb,
                                              float* __restrict__ P,
                                              const int* __restrict__ flag) {
  const int bid = blockIdx.x, t = threadIdx.x;
  const bool isbf = (*flag != 0);
  if (bid == 0) {
    if (t < CMn) bcm_d[t] = ldin(b_cm, t, isbf);
    if (t < Cn)  bdc_d[t] = ldin(b_dcn, t, isbf);
    return;
  }
  if (bid < 1 + 1008) {                       // w_cm -> [18][224][128B swz]
    int i = (bid - 1) * 256 + t;
    if (i >= 18 * 224 * 64) return;
    int s = i / (224 * 64);
    int rem = i % (224 * 64);
    int oc = rem >> 6, c_off = rem & 63;
    int tap = s >> 1, ck = s & 1;
    int c = ck * 64 + c_off;
    float v = 0.f;
    if (oc < CMn) v = ldin(w_cm, ((long)oc * Cn + c) * Kn + tap, isbf);
    int chunk = c_off >> 3, e = c_off & 7;
    int pc = chunk ^ (oc & 7);
    wcb[(long)s * 14336 + oc * 64 + pc * 8 + e] = f2b(v);
    return;
  }
  if (bid < 1 + 1008 + 576) {                 // w_dcn -> [k][ks][o][lh][8]
    int i = (bid - 1 - 1008) * 256 + t;
    if (i >= Kn * Cn * Cn) return;
    int e = i & 7, lh = (i >> 3) & 3, o = (i >> 5) & 127;
    int ks = (i >> 12) & 3, k = i >> 14;
    int c = ks * 32 + lh * 8 + e;
    wdb[i] = f2b(ldin(w_dcn, ((long)o * Cn + c) * Kn + k, isbf));
    return;
  }
  {                                           // P = w_off[:, :128] @ w_fsm
    int idx = (bid - 1 - 1008 - 576) * 256 + t;
    if (idx >= Cn * Cn) return;
    int o = idx >> 7, k = idx & 127;
    float s = 0.f;
    for (int c = 0; c < Cn; ++c)
      s += ldin(woff, (long)o * 256 + c, isbf) * ldin(wfsm, (long)c * Cn + k, isbf);
    P[idx] = s;
  }
}

// ---------------- fused feat_l->flb (+gap) and feat_s->fupb ----------------
__global__ __launch_bounds__(256) void k_cvtlup(const void* __restrict__ feat_l,
                                                const void* __restrict__ fs,
                                                unsigned short* __restrict__ flb,
                                                unsigned short* __restrict__ fupb,
                                                float* __restrict__ gap,
                                                const int* __restrict__ flag) {
  __shared__ float sh[8448];
  const int b = blockIdx.y, t = threadIdx.x;
  const bool isbf = (*flag != 0);
  if (blockIdx.z == 0) {
    const int p0 = blockIdx.x * 64;
    for (int i = t; i < 8192; i += 256) {
      int c = i >> 6, p = i & 63;
      sh[c * 65 + p] = ldin(feat_l, (long)(b * Cn + c) * HWn + p0 + p, isbf);
    }
    __syncthreads();
    if (t < 128) {
      float s = 0.f;
#pragma unroll
      for (int p = 0; p < 64; ++p) s += sh[t * 65 + p];
      atomicAdd(&gap[b * Cn + t], s * (1.0f / HWn));
    }
    for (int i = t; i < 1024; i += 256) {
      int p = i >> 4, ch = (i & 15) * 8;
      uint4 pk;
      pk.x = pack2(sh[(ch + 0) * 65 + p], sh[(ch + 1) * 65 + p]);
      pk.y = pack2(sh[(ch + 2) * 65 + p], sh[(ch + 3) * 65 + p]);
      pk.z = pack2(sh[(ch + 4) * 65 + p], sh[(ch + 5) * 65 + p]);
      pk.w = pack2(sh[(ch + 6) * 65 + p], sh[(ch + 7) * 65 + p]);
      *(uint4*)(flb + (((long)(b * HWn + p0 + p)) << 7) + ch) = pk;
    }
  } else {
    const int h = blockIdx.x;
    int iy0; float fy;
    if (h & 1) { iy0 = (h - 1) >> 1; fy = 0.25f; } else { iy0 = (h >> 1) - 1; fy = 0.75f; }
    int iy1 = min(iy0 + 1, Hs - 1); iy0 = max(iy0, 0);
    for (int i = t; i < 8192; i += 256) {
      int sel = i >> 12, c = (i >> 5) & 127, x = i & 31;
      int iy = sel ? iy1 : iy0;
      sh[sel * 4224 + c * 33 + x] = ldin(fs, (long)(b * Cn + c) * HWs + iy * Ws + x, isbf);
    }
    __syncthreads();
    for (int i = t; i < 1024; i += 256) {
      int w = i >> 4, ch0 = (i & 15) * 8;
      int ix0; float fx;
      if (w & 1) { ix0 = (w - 1) >> 1; fx = 0.25f; } else { ix0 = (w >> 1) - 1; fx = 0.75f; }
      int ix1 = min(ix0 + 1, Ws - 1); ix0 = max(ix0, 0);
      float v[8];
#pragma unroll
      for (int j = 0; j < 8; ++j) {
        int c = ch0 + j;
        v[j] = (1.f - fy) * ((1.f - fx) * sh[c * 33 + ix0] + fx * sh[c * 33 + ix1]) +
               fy         * ((1.f - fx) * sh[4224 + c * 33 + ix0] + fx * sh[4224 + c * 33 + ix1]);
      }
      uint4 pk;
      pk.x = pack2(v[0], v[1]); pk.y = pack2(v[2], v[3]);
      pk.z = pack2(v[4], v[5]); pk.w = pack2(v[6], v[7]);
      *(uint4*)(fupb + (((long)(b * HWn + h * Wn + w)) << 7) + ch0) = pk;
    }
  }
}

// ---------------- atten ----------------
__global__ __launch_bounds__(256) void k_atten(const float* __restrict__ gap,
                                               const void* __restrict__ wat,
                                               float* __restrict__ at1p,
                                               const int* __restrict__ flag) {
  int tid = blockIdx.x * 256 + threadIdx.x;
  if (tid >= Bn * Cn) return;
  int b = tid >> 7, o = tid & 127;
  bool isbf = (*flag != 0);
  const float* g = gap + b * Cn;
  float s = 0.f;
  for (int c = 0; c < Cn; ++c) s += g[c] * ldin(wat, (long)o * Cn + c, isbf);
  at1p[tid] = 1.0f + 1.0f / (1.0f + expf(-s));
}

// ---------------- per-batch weight prep ----------------
__global__ __launch_bounds__(256) void k_wprep(const void* __restrict__ wfsm,
                                               const void* __restrict__ woff,
                                               const float* __restrict__ P,
                                               const float* __restrict__ at1p,
                                               unsigned short* __restrict__ w1tb,
                                               unsigned short* __restrict__ wcat,
                                               const int* __restrict__ flag) {
  int idx = blockIdx.x * 256 + threadIdx.x;
  if (idx >= Bn * 49152) return;
  bool isbf = (*flag != 0);
  int b = idx / 49152, r = idx % 49152;
  if (r < 16384) {
    int o = r >> 7, k = r & 127;
    w1tb[((long)(b * Cn + o) << 7) + k] =
        f2b(ldin(wfsm, (long)o * Cn + k, isbf) * at1p[b * Cn + k]);
  } else {
    r -= 16384;
    int o = r >> 8, k = r & 255;
    float v = (k < 128) ? P[o * Cn + k] * at1p[b * Cn + k]
                        : 2.0f * ldin(woff, (long)o * 256 + k, isbf);
    wcat[((long)(b * Cn + o) << 8) + k] = f2b(v);
  }
}

// ---------------- fused feat_arm + off_feat via MFMA (M-tile 32) ----------------
__global__ __launch_bounds__(256) void k_fao(const unsigned short* __restrict__ flb,
                                             const unsigned short* __restrict__ fupb,
                                             const unsigned short* __restrict__ w1tb,
                                             const unsigned short* __restrict__ wcat,
                                             unsigned short* __restrict__ farm,
                                             unsigned short* __restrict__ oftb) {
  const int b = blockIdx.y, m0 = blockIdx.x * 32;
  const int t = threadIdx.x, lane = t & 63, wv = t >> 6;
  const int lm = lane & 15, lh = lane >> 4;
  f32x4 accF[2][2], accO[2][2];
#pragma unroll
  for (int mt = 0; mt < 2; ++mt)
#pragma unroll
    for (int nt = 0; nt < 2; ++nt) {
      accF[mt][nt] = (f32x4){0.f, 0.f, 0.f, 0.f};
      accO[mt][nt] = (f32x4){0.f, 0.f, 0.f, 0.f};
    }
  const unsigned short* A0 = flb + ((long)b << 19);
  const unsigned short* A1 = fupb + ((long)b << 19);
  const unsigned short* BwF = w1tb + ((long)b << 14);
  const unsigned short* BwO = wcat + ((long)b << 15);
#pragma unroll
  for (int ks = 0; ks < 4; ++ks) {
    int c0 = ks * 32 + lh * 8;
    bf16x8 bfvF[2], bfvO[2];
#pragma unroll
    for (int nt = 0; nt < 2; ++nt) {
      int o = wv * 32 + nt * 16 + lm;
      bfvF[nt] = *(const bf16x8*)(BwF + ((long)o << 7) + c0);
      bfvO[nt] = *(const bf16x8*)(BwO + ((long)o << 8) + c0);
    }
#pragma unroll
    for (int mt = 0; mt < 2; ++mt) {
      bf16x8 af = *(const bf16x8*)(A0 + (((long)(m0 + mt * 16 + lm)) << 7) + c0);
#pragma unroll
      for (int nt = 0; nt < 2; ++nt) {
        accF[mt][nt] = __builtin_amdgcn_mfma_f32_16x16x32_bf16(af, bfvF[nt], accF[mt][nt], 0, 0, 0);
        accO[mt][nt] = __builtin_amdgcn_mfma_f32_16x16x32_bf16(af, bfvO[nt], accO[mt][nt], 0, 0, 0);
      }
    }
  }
#pragma unroll
  for (int ks = 4; ks < 8; ++ks) {
    int c0 = ks * 32 + lh * 8;
    int ca = c0 - 128;
    bf16x8 bfvO[2];
#pragma unroll
    for (int nt = 0; nt < 2; ++nt)
      bfvO[nt] = *(const bf16x8*)(BwO + (((long)(wv * 32 + nt * 16 + lm)) << 8) + c0);
#pragma unroll
    for (int mt = 0; mt < 2; ++mt) {
      bf16x8 af = *(const bf16x8*)(A1 + (((long)(m0 + mt * 16 + lm)) << 7) + ca);
#pragma unroll
      for (int nt = 0; nt < 2; ++nt)
        accO[mt][nt] = __builtin_amdgcn_mfma_f32_16x16x32_bf16(af, bfvO[nt], accO[mt][nt], 0, 0, 0);
    }
  }
#pragma unroll
  for (int nt = 0; nt < 2; ++nt) {
    int o = wv * 32 + nt * 16 + lm;
#pragma unroll
    for (int mt = 0; mt < 2; ++mt) {
      uint2 pw;
      pw.x = pack2(accF[mt][nt][0], accF[mt][nt][1]);
      pw.y = pack2(accF[mt][nt][2], accF[mt][nt][3]);
      *(uint2*)(farm + (((long)(b * Cn + o)) << 12) + m0 + mt * 16 + lh * 4) = pw;
#pragma unroll
      for (int r = 0; r < 4; ++r)
        oftb[(((long)(b * HWn + m0 + mt * 16 + lh * 4 + r)) << 7) + o] = f2b(accO[mt][nt][r]);
    }
  }
}

// ---------------- 3x3 conv via bf16 MFMA -> om (bf16), XCD-localized ----------------
__global__ __launch_bounds__(256) void k_convcm(const unsigned short* __restrict__ xb,
                                                const unsigned short* __restrict__ wsl,
                                                const float* __restrict__ bcm,
                                                unsigned short* __restrict__ om) {
  __shared__ unsigned short wlds[2][14336];
  const int bid = blockIdx.x;
  const int b = bid & 7, h = bid >> 3;
  const int t = threadIdx.x, lane = t & 63, wv = t >> 6;
  const int mi = wv & 1, ni = wv >> 1;
  const int lm = lane & 15, lh = lane >> 4;

  f32x4 acc[2][7];
#pragma unroll
  for (int mt = 0; mt < 2; ++mt)
#pragma unroll
    for (int nt = 0; nt < 7; ++nt) acc[mt][nt] = (f32x4){0.f, 0.f, 0.f, 0.f};

  auto stage = [&](int s, int bufi) {
    const char* src = (const char*)(wsl + (long)s * 14336);
    char* dstb = (char*)&wlds[bufi][0];
#pragma unroll
    for (int i2 = 0; i2 < 7; ++i2) {
      int off = (wv * 7 + i2) * 1024;
      GLOAD_LDS16(src + off + lane * 16, dstb + off);
    }
  };

  stage(0, 0);
  __syncthreads();

  for (int s = 0; s < 18; ++s) {
    const int cur = s & 1;
    if (s < 17) stage(s + 1, cur ^ 1);
    const int tap = s >> 1, ck = s & 1;
    const int ky = tap / 3, kx = tap % 3;
    const int gy = h + ky - 1;
    const bool gyok = ((unsigned)gy < (unsigned)Hn);
    const int gyc = min(max(gy, 0), Hn - 1);

    bf16x8 af[2][2];
#pragma unroll
    for (int mt = 0; mt < 2; ++mt) {
      int wpos = mi * 32 + mt * 16 + lm;
      int gx = wpos + kx - 1;
      bool ok = gyok && ((unsigned)gx < (unsigned)Wn);
      int gxc = min(max(gx, 0), Wn - 1);
      const unsigned short* ap = xb + (((long)(b * HWn + gyc * Wn + gxc)) << 7)
                                    + ck * 64 + lh * 8;
#pragma unroll
      for (int ksub = 0; ksub < 2; ++ksub) {
        bf16x8 v = *(const bf16x8*)(ap + ksub * 32);
        af[mt][ksub] = ok ? v : (bf16x8)(short)0;
      }
    }

    const char* wbase = (const char*)&wlds[cur][0];
#pragma unroll
    for (int ksub = 0; ksub < 2; ++ksub) {
      int jj = ksub * 4 + lh;
#pragma unroll
      for (int nt = 0; nt < 7; ++nt) {
        int oc = ni * 112 + nt * 16 + lm;
        bf16x8 bfv = *(const bf16x8*)(wbase + oc * 128 + ((jj ^ (oc & 7)) << 4));
#pragma unroll
        for (int mt = 0; mt < 2; ++mt)
          acc[mt][nt] = __builtin_amdgcn_mfma_f32_16x16x32_bf16(
              af[mt][ksub], bfv, acc[mt][nt], 0, 0, 0);
      }
    }
    __syncthreads();
  }

#pragma unroll
  for (int nt = 0; nt < 7; ++nt) {
    int ch = ni * 112 + nt * 16 + lm;
    if (ch >= CMn) continue;
    float bias = bcm[ch];
#pragma unroll
    for (int mt = 0; mt < 2; ++mt) {
#pragma unroll
      for (int r = 0; r < 4; ++r) {
        int w = mi * 32 + mt * 16 + lh * 4 + r;
        float v = acc[mt][nt][r] + bias;
        if (ch >= 144) v = 1.0f / (1.0f + expf(-v));
        om[((long)((b * Hn + h) * CMn + ch) << 6) + w] = f2b(v);
      }
    }
  }
}

// ---------------- fused DCN v2: producer/consumer, bf16 om, XCD-localized (R16) ----------------
__global__ __launch_bounds__(512, 8) void k_dcn(const unsigned short* __restrict__ omb,
                                                const unsigned short* __restrict__ fupb,
                                                const unsigned short* __restrict__ wdb,
                                                const float* __restrict__ bdc,
                                                const unsigned short* __restrict__ farm,
                                                void* __restrict__ out,
                                                const int* __restrict__ flagp) {
  __shared__ char smem[13824 + 16384];
  unsigned short* om16 = (unsigned short*)smem;       // [216][32] bf16
  const int bid = blockIdx.x;
  const int b = bid & 7, hw = bid >> 3;
  const int h = hw >> 1, w0 = (hw & 1) * 32;
  const int t = threadIdx.x;
  const int lane = t & 63, wid = t >> 6;
  const int lm = lane & 15, lh = lane >> 4;

  // ---- om preload: 216 rows x 32 bf16 ----
  const unsigned short* omr = omb + ((long)(b * Hn + h) * CMn << 6) + w0;
  for (int i = t; i < 864; i += 512) {
    int ch = i >> 2, q = i & 3;
    *(uint4*)(om16 + ch * 32 + q * 8) = *(const uint4*)(omr + (ch << 6) + q * 8);
  }

  // producer identity: lane pairs share corner lines
  const int pid = (wid << 6) | lane;
  const int half = pid & 1, gw = (pid >> 1) & 31, gg = pid >> 6;
  const int wcol = w0 + gw;
  const unsigned short* fbb = fupb + ((long)b << 19) + half * 8;

  // consumer identity
  const int cw = wid - 4;
  f32x4 acc[2][2];
#pragma unroll
  for (int mt = 0; mt < 2; ++mt)
#pragma unroll
    for (int nt = 0; nt < 2; ++nt) acc[mt][nt] = (f32x4){0.f, 0.f, 0.f, 0.f};

  union U4 { uint4 q; unsigned short s[8]; };

  auto stage = [&](int k) {
#pragma unroll
    for (int ti = 0; ti < 2; ++ti) {
      const int g = gg + ti * 4;
      const unsigned short* fb = fbb + g * 16;
      int ch = g * Kn + k;
      float oy = b2f(om16[ch * 32 + gw]);
      float ox = b2f(om16[(72 + ch) * 32 + gw]);
      float mk = b2f(om16[(144 + ch) * 32 + gw]);
      float py = (float)(h + k / 3 - 1) + oy;
      float px = (float)(wcol + k % 3 - 1) + ox;
      float fy = floorf(py), fx = floorf(px);
      float ly = py - fy, lx = px - fx;
      int y0 = (int)fy, x0 = (int)fx, y1 = y0 + 1, x1 = x0 + 1;
      float vy0 = (y0 >= 0 && y0 < Hn) ? 1.f : 0.f;
      float vy1 = (y1 >= 0 && y1 < Hn) ? 1.f : 0.f;
      float vx0 = (x0 >= 0 && x0 < Wn) ? 1.f : 0.f;
      float vx1 = (x1 >= 0 && x1 < Wn) ? 1.f : 0.f;
      int cy0 = min(max(y0, 0), Hn - 1), cy1 = min(max(y1, 0), Hn - 1);
      int cx0 = min(max(x0, 0), Wn - 1), cx1 = min(max(x1, 0), Wn - 1);
      float wq0 = (1.f - ly) * (1.f - lx) * vy0 * vx0 * mk;
      float wq1 = (1.f - ly) * lx * vy0 * vx1 * mk;
      float wq2 = ly * (1.f - lx) * vy1 * vx0 * mk;
      float wq3 = ly * lx * vy1 * vx1 * mk;
      U4 a0, a1, a2, a3;
      a0.q = *(const uint4*)(fb + ((long)(cy0 * Wn + cx0) << 7));
      a1.q = *(const uint4*)(fb + ((long)(cy0 * Wn + cx1) << 7));
      a2.q = *(const uint4*)(fb + ((long)(cy1 * Wn + cx0) << 7));
      a3.q = *(const uint4*)(fb + ((long)(cy1 * Wn + cx1) << 7));
      float v[8];
#pragma unroll
      for (int j = 0; j < 8; ++j)
        v[j] = wq0 * b2f(a0.s[j]) + wq1 * b2f(a1.s[j]) +
               wq2 * b2f(a2.s[j]) + wq3 * b2f(a3.s[j]);
      uint4 pk;
      pk.x = pack2(v[0], v[1]); pk.y = pack2(v[2], v[3]);
      pk.z = pack2(v[4], v[5]); pk.w = pack2(v[6], v[7]);
      int chunk = g * 2 + half;
      *(uint4*)(smem + 13824 + (k & 1) * 8192 + gw * 256 + ((chunk ^ (gw & 15)) << 4)) = pk;
    }
  };

  __syncthreads();            // om16 ready
  if (wid < 4) stage(0);
  __syncthreads();            // buf0 ready

#pragma unroll
  for (int k = 0; k < Kn; ++k) {
    if (wid < 4) {
      if (k < Kn - 1) stage(k + 1);
    } else {
      const char* base = smem + 13824 + (k & 1) * 8192;
      const unsigned short* wk = wdb + (long)k * 16384;
      __builtin_amdgcn_s_setprio(1);
#pragma unroll
      for (int ks = 0; ks < 4; ++ks) {
        int rchunk = (ks * 4 + lh) ^ lm;
        bf16x8 af0 = *(const bf16x8*)(base + lm * 256 + (rchunk << 4));
        bf16x8 af1 = *(const bf16x8*)(base + (16 + lm) * 256 + (rchunk << 4));
#pragma unroll
        for (int nt = 0; nt < 2; ++nt) {
          bf16x8 bfv = *(const bf16x8*)(wk + ks * 4096 +
                                        ((cw * 32 + nt * 16 + lm) << 5) + lh * 8);
          acc[0][nt] = __builtin_amdgcn_mfma_f32_16x16x32_bf16(af0, bfv, acc[0][nt], 0, 0, 0);
          acc[1][nt] = __builtin_amdgcn_mfma_f32_16x16x32_bf16(af1, bfv, acc[1][nt], 0, 0, 0);
        }
      }
      __builtin_amdgcn_s_setprio(0);
    }
    __syncthreads();
  }

  // ---- epilogue: acc -> padded LDS -> w-major coalesced farm+out ----
  float* eps = (float*)smem;
  if (wid >= 4) {
#pragma unroll
    for (int nt = 0; nt < 2; ++nt) {
      int o = cw * 32 + nt * 16 + lm;
#pragma unroll
      for (int mt = 0; mt < 2; ++mt)
#pragma unroll
        for (int r = 0; r < 4; ++r)
          eps[o * 33 + mt * 16 + lh * 4 + r] = acc[mt][nt][r];
    }
  }
  __syncthreads();
  {
    bool isbf = (*flagp != 0);
    int o = t >> 2, q = t & 3;            // 128 o x 4 q(8w each)
    float bias = bdc[o];
    long obase = (long)(b * Cn + o) * HWn + h * Wn + w0 + q * 8;
    U4 fv;
    fv.q = *(const uint4*)(farm + obase);
    float vout[8];
#pragma unroll
    for (int j = 0; j < 8; ++j) {
      float v = eps[o * 33 + q * 8 + j] + bias;
      vout[j] = fmaxf(v, 0.f) + b2f(fv.s[j]);
    }
    if (isbf) {
      uint4 pk;
      pk.x = pack2(vout[0], vout[1]); pk.y = pack2(vout[2], vout[3]);
      pk.z = pack2(vout[4], vout[5]); pk.w = pack2(vout[6], vout[7]);
      *(uint4*)((__hip_bfloat16*)out + obase) = pk;
    } else {
      float* op = (float*)out + obase;
      *(float4*)op = (float4){vout[0], vout[1], vout[2], vout[3]};
      *(float4*)(op + 4) = (float4){vout[4], vout[5], vout[6], vout[7]};
    }
  }
}

// ---------------- launcher ----------------
extern "C" void kernel_launch(void* const* d_in, const int* in_sizes, int n_in,
                              void* d_out, int out_size, void* d_ws, size_t ws_size,
                              hipStream_t stream) {
  (void)in_sizes; (void)n_in; (void)out_size; (void)ws_size;
  const void* feat_l  = d_in[0];
  const void* feat_s  = d_in[1];
  const void* w_atten = d_in[2];
  const void* w_fsm   = d_in[3];
  const void* w_off   = d_in[4];
  const void* w_cm    = d_in[5];
  const void* b_cm    = d_in[6];
  const void* w_dcn   = d_in[7];
  const void* b_dcn   = d_in[8];
  float* ws = (float*)d_ws;
  int* flagw = (int*)d_ws;
  const int* flag = (const int*)d_ws;
  unsigned short* flb  = (unsigned short*)(ws + OFF_FLB);
  unsigned short* fupb = (unsigned short*)(ws + OFF_FUPB);
  unsigned short* oftb = (unsigned short*)(ws + OFF_OFT);
  unsigned short* wcb  = (unsigned short*)(ws + OFF_WCT);
  unsigned short* wdb  = (unsigned short*)(ws + OFF_WDT);
  unsigned short* w1tb = (unsigned short*)(ws + OFF_W1TB);
  unsigned short* wcat = (unsigned short*)(ws + OFF_WCAT);
  unsigned short* farm = (unsigned short*)(ws + OFF_FARM);
  unsigned short* omb  = (unsigned short*)(ws + OFF_OM);

  k_detect<<<1, 256, 0, stream>>>((const unsigned int*)feat_l, flagw, ws + OFF_GAP);
  k_prep<<<1 + 1008 + 576 + 64, 256, 0, stream>>>(b_cm, b_dcn, w_cm, w_dcn,
                                                  w_off, w_fsm,
                                                  ws + OFF_BCM, ws + OFF_BDC,
                                                  wcb, wdb, ws + OFF_P, flag);
  k_cvtlup<<<dim3(64, 8, 2), 256, 0, stream>>>(feat_l, feat_s, flb, fupb,
                                               ws + OFF_GAP, flag);
  k_atten<<<4, 256, 0, stream>>>(ws + OFF_GAP, w_atten, ws + OFF_AT, flag);
  k_wprep<<<(Bn * 49152 + 255) / 256, 256, 0, stream>>>(w_fsm, w_off, ws + OFF_P,
                                                        ws + OFF_AT, w1tb, wcat, flag);
  k_fao<<<dim3(128, 8), 256, 0, stream>>>(flb, fupb, w1tb, wcat, farm, oftb);
  k_convcm<<<512, 256, 0, stream>>>(oftb, wcb, ws + OFF_BCM, omb);
  k_dcn<<<1024, 512, 0, stream>>>(omb, fupb, wdb, ws + OFF_BDC, farm, d_out, flag);
}